// Round 1
// baseline (5947.210 us; speedup 1.0000x reference)
//
#include <hip/hip_runtime.h>

#define DIN 512
#define DH  64

// ---------------- small precompute: Wc = W2@Wlin, bias_out = b2@Wlin + blin ----
__global__ __launch_bounds__(256) void k_wc(const float* __restrict__ W2,
                                            const float* __restrict__ b2,
                                            const float* __restrict__ Wlin,
                                            const float* __restrict__ blin,
                                            float* __restrict__ Wc,
                                            float* __restrict__ bias_out) {
  int tid = threadIdx.x;
  for (int idx = tid; idx < 64 * 64; idx += 256) {
    int i = idx >> 6, j = idx & 63;
    float s = 0.f;
    #pragma unroll 8
    for (int k = 0; k < 64; ++k) s = fmaf(W2[i * 64 + k], Wlin[k * 64 + j], s);
    Wc[idx] = s;
  }
  if (tid < 64) {
    float s = blin[tid];
    #pragma unroll 8
    for (int k = 0; k < 64; ++k) s = fmaf(b2[k], Wlin[k * 64 + tid], s);
    bias_out[tid] = s;
  }
}

// ---------------- degree ------------------------------------------------------
__global__ __launch_bounds__(256) void k_deg(const int* __restrict__ dst, int n_edges,
                                             int* __restrict__ degi) {
  int t = blockIdx.x * 256 + threadIdx.x;
  if (t < n_edges) atomicAdd(&degi[dst[t]], 1);
}

__global__ __launch_bounds__(256) void k_dinv(const int* __restrict__ degi,
                                              float* __restrict__ dinv, int n) {
  int t = blockIdx.x * 256 + threadIdx.x;
  if (t < n) dinv[t] = rsqrtf((float)(degi[t] + 1));  // +1 = self loop
}

// ---------------- fp32 tiled GEMM: C[M,64] = A[M,K] @ B[K,64] -----------------
// block tile 64x64, thread tile 4x4, K chunk 16
__global__ __launch_bounds__(256) void k_gemm(const float* __restrict__ A,
                                              const float* __restrict__ B,
                                              float* __restrict__ C,
                                              int M, int K) {
  __shared__ float As[16][68];  // [k][m], padded
  __shared__ float Bs[16][64];  // [k][n]
  const int tid = threadIdx.x;
  const int block_m = blockIdx.x * 64;
  const int tm = (tid >> 4) * 4;      // 0..60
  const int tn = (tid & 15) * 4;      // 0..60
  const int lm = tid >> 2;            // 0..63 node within tile (A load)
  const int lk = (tid & 3) * 4;       // 0,4,8,12 (A load)
  const int bk = tid >> 4;            // 0..15 (B load)
  const int bn = (tid & 15) * 4;      // (B load)

  float acc[4][4] = {{0.f}};

  for (int k0 = 0; k0 < K; k0 += 16) {
    float4 a = make_float4(0.f, 0.f, 0.f, 0.f);
    int an = block_m + lm;
    if (an < M) a = *(const float4*)&A[(size_t)an * K + k0 + lk];
    As[lk + 0][lm] = a.x;
    As[lk + 1][lm] = a.y;
    As[lk + 2][lm] = a.z;
    As[lk + 3][lm] = a.w;
    *(float4*)&Bs[bk][bn] = *(const float4*)&B[(size_t)(k0 + bk) * 64 + bn];
    __syncthreads();
    #pragma unroll
    for (int k = 0; k < 16; ++k) {
      float4 av = *(const float4*)&As[k][tm];
      float4 bv = *(const float4*)&Bs[k][tn];
      acc[0][0] = fmaf(av.x, bv.x, acc[0][0]);
      acc[0][1] = fmaf(av.x, bv.y, acc[0][1]);
      acc[0][2] = fmaf(av.x, bv.z, acc[0][2]);
      acc[0][3] = fmaf(av.x, bv.w, acc[0][3]);
      acc[1][0] = fmaf(av.y, bv.x, acc[1][0]);
      acc[1][1] = fmaf(av.y, bv.y, acc[1][1]);
      acc[1][2] = fmaf(av.y, bv.z, acc[1][2]);
      acc[1][3] = fmaf(av.y, bv.w, acc[1][3]);
      acc[2][0] = fmaf(av.z, bv.x, acc[2][0]);
      acc[2][1] = fmaf(av.z, bv.y, acc[2][1]);
      acc[2][2] = fmaf(av.z, bv.z, acc[2][2]);
      acc[2][3] = fmaf(av.z, bv.w, acc[2][3]);
      acc[3][0] = fmaf(av.w, bv.x, acc[3][0]);
      acc[3][1] = fmaf(av.w, bv.y, acc[3][1]);
      acc[3][2] = fmaf(av.w, bv.z, acc[3][2]);
      acc[3][3] = fmaf(av.w, bv.w, acc[3][3]);
    }
    __syncthreads();
  }
  #pragma unroll
  for (int i = 0; i < 4; ++i) {
    int row = block_m + tm + i;
    if (row < M) {
      float4 r = make_float4(acc[i][0], acc[i][1], acc[i][2], acc[i][3]);
      *(float4*)&C[(size_t)row * 64 + tn] = r;
    }
  }
}

// ---------------- edge aggregation: out[dst] += feat[src] * dinv[s]*dinv[d] ---
// 16 threads per edge, float4 per thread, hardware fp32 atomics
__global__ __launch_bounds__(256) void k_edge(const float* __restrict__ feat,
                                              const int* __restrict__ src,
                                              const int* __restrict__ dst,
                                              const float* __restrict__ dinv,
                                              float* __restrict__ out,
                                              int n_edges) {
  long long t = (long long)blockIdx.x * 256 + threadIdx.x;
  int e = (int)(t >> 4);
  if (e >= n_edges) return;
  int c = ((int)t & 15) << 2;
  int s = src[e], d = dst[e];
  float w = dinv[s] * dinv[d];
  float4 v = *(const float4*)&feat[(size_t)s * 64 + c];
  float* o = &out[(size_t)d * 64 + c];
  unsafeAtomicAdd(o + 0, v.x * w);
  unsafeAtomicAdd(o + 1, v.y * w);
  unsafeAtomicAdd(o + 2, v.z * w);
  unsafeAtomicAdd(o + 3, v.w * w);
}

// ---------------- post layer 1: h1r = relu(agg + h*dinv^2 + b1), in place -----
__global__ __launch_bounds__(256) void k_post1(const float* __restrict__ agg,
                                               const float* __restrict__ h,
                                               const float* __restrict__ dinv,
                                               const float* __restrict__ b1,
                                               float* __restrict__ outp,
                                               int n_nodes) {
  int t = blockIdx.x * 256 + threadIdx.x;  // one float4 per thread
  if (t >= n_nodes * 16) return;
  int i = t >> 4;
  int c = (t & 15) << 2;
  float di = dinv[i];
  float w = di * di;
  float4 av = *(const float4*)&agg[(size_t)t * 4];
  float4 hv = *(const float4*)&h[(size_t)t * 4];
  float4 bv = *(const float4*)&b1[c];
  float4 r;
  r.x = fmaxf(fmaf(hv.x, w, av.x) + bv.x, 0.f);
  r.y = fmaxf(fmaf(hv.y, w, av.y) + bv.y, 0.f);
  r.z = fmaxf(fmaf(hv.z, w, av.z) + bv.z, 0.f);
  r.w = fmaxf(fmaf(hv.w, w, av.w) + bv.w, 0.f);
  *(float4*)&outp[(size_t)t * 4] = r;
}

// ---------------- post layer 2: out += h2*dinv^2 + bias_out -------------------
__global__ __launch_bounds__(256) void k_post2(const float* __restrict__ h2,
                                               const float* __restrict__ dinv,
                                               const float* __restrict__ bias,
                                               float* __restrict__ out,
                                               int n_nodes) {
  int t = blockIdx.x * 256 + threadIdx.x;
  if (t >= n_nodes * 16) return;
  int i = t >> 4;
  int c = (t & 15) << 2;
  float di = dinv[i];
  float w = di * di;
  float4 hv = *(const float4*)&h2[(size_t)t * 4];
  float4 bv = *(const float4*)&bias[c];
  float4 ov = *(const float4*)&out[(size_t)t * 4];
  ov.x += fmaf(hv.x, w, bv.x);
  ov.y += fmaf(hv.y, w, bv.y);
  ov.z += fmaf(hv.z, w, bv.z);
  ov.w += fmaf(hv.w, w, bv.w);
  *(float4*)&out[(size_t)t * 4] = ov;
}

extern "C" void kernel_launch(void* const* d_in, const int* in_sizes, int n_in,
                              void* d_out, int out_size, void* d_ws, size_t ws_size,
                              hipStream_t stream) {
  const float* x    = (const float*)d_in[0];
  const int*   ei   = (const int*)d_in[1];
  const float* W1   = (const float*)d_in[2];
  const float* b1   = (const float*)d_in[3];
  const float* W2   = (const float*)d_in[4];
  const float* b2   = (const float*)d_in[5];
  const float* Wlin = (const float*)d_in[6];
  const float* blin = (const float*)d_in[7];
  float* out = (float*)d_out;

  const int n_nodes = in_sizes[0] / DIN;
  const int n_edges = in_sizes[1] / 2;
  const int* src = ei;
  const int* dst = ei + n_edges;

  char* ws = (char*)d_ws;
  const size_t featBytes = (size_t)n_nodes * DH * sizeof(float);
  float* bufA = (float*)ws;                          // h1, then h2
  float* bufB = (float*)(ws + featBytes);            // agg1, then h1r
  int*   degi = (int*)(ws + 2 * featBytes);
  float* dinv = (float*)(ws + 2 * featBytes + (size_t)n_nodes * 4);
  float* Wc   = (float*)(ws + 2 * featBytes + 2 * (size_t)n_nodes * 4);
  float* bias_out = Wc + 64 * 64;

  hipMemsetAsync(degi, 0, (size_t)n_nodes * 4, stream);
  hipMemsetAsync(bufB, 0, featBytes, stream);
  hipMemsetAsync(d_out, 0, featBytes, stream);

  k_wc<<<1, 256, 0, stream>>>(W2, b2, Wlin, blin, Wc, bias_out);
  k_deg<<<(n_edges + 255) / 256, 256, 0, stream>>>(dst, n_edges, degi);
  k_dinv<<<(n_nodes + 255) / 256, 256, 0, stream>>>(degi, dinv, n_nodes);

  const int gblocks = (n_nodes + 63) / 64;
  const int eblocks = (int)(((long long)n_edges * 16 + 255) / 256);
  const int pblocks = (n_nodes * 16 + 255) / 256;

  // layer 1
  k_gemm<<<gblocks, 256, 0, stream>>>(x, W1, bufA, n_nodes, DIN);
  k_edge<<<eblocks, 256, 0, stream>>>(bufA, src, dst, dinv, bufB, n_edges);
  k_post1<<<pblocks, 256, 0, stream>>>(bufB, bufA, dinv, b1, bufB, n_nodes);

  // layer 2 (+ folded final linear): h2 = h1r @ (W2@Wlin)
  k_gemm<<<gblocks, 256, 0, stream>>>(bufB, Wc, bufA, n_nodes, DH);
  k_edge<<<eblocks, 256, 0, stream>>>(bufA, src, dst, dinv, out, n_edges);
  k_post2<<<pblocks, 256, 0, stream>>>(bufA, dinv, bias_out, out, n_nodes);
}

// Round 2
// 922.077 us; speedup vs baseline: 6.4498x; 6.4498x over previous
//
#include <hip/hip_runtime.h>

#define DIN 512
#define DH  64

// ---------------- small precompute: Wc = W2@Wlin, bias_out = b2@Wlin + blin ----
__global__ __launch_bounds__(256) void k_wc(const float* __restrict__ W2,
                                            const float* __restrict__ b2,
                                            const float* __restrict__ Wlin,
                                            const float* __restrict__ blin,
                                            float* __restrict__ Wc,
                                            float* __restrict__ bias_out) {
  int tid = threadIdx.x;
  for (int idx = tid; idx < 64 * 64; idx += 256) {
    int i = idx >> 6, j = idx & 63;
    float s = 0.f;
    #pragma unroll 8
    for (int k = 0; k < 64; ++k) s = fmaf(W2[i * 64 + k], Wlin[k * 64 + j], s);
    Wc[idx] = s;
  }
  if (tid < 64) {
    float s = blin[tid];
    #pragma unroll 8
    for (int k = 0; k < 64; ++k) s = fmaf(b2[k], Wlin[k * 64 + tid], s);
    bias_out[tid] = s;
  }
}

// ---------------- degree ------------------------------------------------------
__global__ __launch_bounds__(256) void k_deg(const int* __restrict__ dst, int n_edges,
                                             int* __restrict__ degi) {
  int t = blockIdx.x * 256 + threadIdx.x;
  if (t < n_edges) atomicAdd(&degi[dst[t]], 1);
}

__global__ __launch_bounds__(256) void k_dinv(const int* __restrict__ degi,
                                              float* __restrict__ dinv, int n) {
  int t = blockIdx.x * 256 + threadIdx.x;
  if (t < n) dinv[t] = rsqrtf((float)(degi[t] + 1));  // +1 = self loop
}

// ---------------- scan: rowptr = exclusive_scan(deg), rowptr[n] = total -------
// chunk = 1024 elems per block (256 thr x 4)
__global__ __launch_bounds__(256) void k_scanA(const int* __restrict__ deg, int n,
                                               int* __restrict__ rowptr,
                                               int* __restrict__ partials) {
  __shared__ int sh[256];
  const int b = blockIdx.x, t = threadIdx.x;
  const int base = b * 1024 + t * 4;
  int v[4];
  int s = 0;
  #pragma unroll
  for (int k = 0; k < 4; ++k) {
    int i = base + k;
    v[k] = (i < n) ? deg[i] : 0;
    s += v[k];
  }
  sh[t] = s;
  __syncthreads();
  for (int off = 1; off < 256; off <<= 1) {
    int x = sh[t];
    int y = (t >= off) ? sh[t - off] : 0;
    __syncthreads();
    sh[t] = x + y;
    __syncthreads();
  }
  int excl = sh[t] - s;
  #pragma unroll
  for (int k = 0; k < 4; ++k) {
    int i = base + k;
    if (i < n) rowptr[i] = excl;
    excl += v[k];
  }
  if (t == 255) partials[b] = sh[255];
}

__global__ void k_scanB(int* __restrict__ partials, int nb, int* __restrict__ rowptr_n) {
  if (threadIdx.x == 0 && blockIdx.x == 0) {
    int s = 0;
    for (int i = 0; i < nb; ++i) {
      int v = partials[i];
      partials[i] = s;
      s += v;
    }
    *rowptr_n = s;  // grand total -> rowptr[n]
  }
}

__global__ __launch_bounds__(256) void k_scanC(int* __restrict__ rowptr,
                                               const int* __restrict__ partials, int n,
                                               int* __restrict__ cursor) {
  int i = blockIdx.x * 256 + threadIdx.x;
  if (i < n) {
    int v = rowptr[i] + partials[i >> 10];
    rowptr[i] = v;
    cursor[i] = v;
  }
}

// ---------------- scatter edges into CSR order (by dst) -----------------------
__global__ __launch_bounds__(256) void k_scatter(const int* __restrict__ src,
                                                 const int* __restrict__ dst,
                                                 const float* __restrict__ dinv,
                                                 int* __restrict__ cursor,
                                                 int2* __restrict__ pairs, int n_edges) {
  int e = blockIdx.x * 256 + threadIdx.x;
  if (e >= n_edges) return;
  int s = src[e], d = dst[e];
  int pos = atomicAdd(&cursor[d], 1);
  float w = dinv[s] * dinv[d];
  pairs[pos] = make_int2(s, __float_as_int(w));
}

// ---------------- fp32 tiled GEMM: C[M,64] = A[M,K] @ B[K,64] -----------------
__global__ __launch_bounds__(256) void k_gemm(const float* __restrict__ A,
                                              const float* __restrict__ B,
                                              float* __restrict__ C,
                                              int M, int K) {
  __shared__ float As[16][68];  // [k][m], padded
  __shared__ float Bs[16][64];  // [k][n]
  const int tid = threadIdx.x;
  const int block_m = blockIdx.x * 64;
  const int tm = (tid >> 4) * 4;
  const int tn = (tid & 15) * 4;
  const int lm = tid >> 2;
  const int lk = (tid & 3) * 4;
  const int bk = tid >> 4;
  const int bn = (tid & 15) * 4;

  float acc[4][4] = {{0.f}};

  for (int k0 = 0; k0 < K; k0 += 16) {
    float4 a = make_float4(0.f, 0.f, 0.f, 0.f);
    int an = block_m + lm;
    if (an < M) a = *(const float4*)&A[(size_t)an * K + k0 + lk];
    As[lk + 0][lm] = a.x;
    As[lk + 1][lm] = a.y;
    As[lk + 2][lm] = a.z;
    As[lk + 3][lm] = a.w;
    *(float4*)&Bs[bk][bn] = *(const float4*)&B[(size_t)(k0 + bk) * 64 + bn];
    __syncthreads();
    #pragma unroll
    for (int k = 0; k < 16; ++k) {
      float4 av = *(const float4*)&As[k][tm];
      float4 bv = *(const float4*)&Bs[k][tn];
      acc[0][0] = fmaf(av.x, bv.x, acc[0][0]);
      acc[0][1] = fmaf(av.x, bv.y, acc[0][1]);
      acc[0][2] = fmaf(av.x, bv.z, acc[0][2]);
      acc[0][3] = fmaf(av.x, bv.w, acc[0][3]);
      acc[1][0] = fmaf(av.y, bv.x, acc[1][0]);
      acc[1][1] = fmaf(av.y, bv.y, acc[1][1]);
      acc[1][2] = fmaf(av.y, bv.z, acc[1][2]);
      acc[1][3] = fmaf(av.y, bv.w, acc[1][3]);
      acc[2][0] = fmaf(av.z, bv.x, acc[2][0]);
      acc[2][1] = fmaf(av.z, bv.y, acc[2][1]);
      acc[2][2] = fmaf(av.z, bv.z, acc[2][2]);
      acc[2][3] = fmaf(av.z, bv.w, acc[2][3]);
      acc[3][0] = fmaf(av.w, bv.x, acc[3][0]);
      acc[3][1] = fmaf(av.w, bv.y, acc[3][1]);
      acc[3][2] = fmaf(av.w, bv.z, acc[3][2]);
      acc[3][3] = fmaf(av.w, bv.w, acc[3][3]);
    }
    __syncthreads();
  }
  #pragma unroll
  for (int i = 0; i < 4; ++i) {
    int row = block_m + tm + i;
    if (row < M) {
      float4 r = make_float4(acc[i][0], acc[i][1], acc[i][2], acc[i][3]);
      *(float4*)&C[(size_t)row * 64 + tn] = r;
    }
  }
}

// ---------------- CSR gather: out[d,:] = sum_e w_e * feat[src_e,:] ------------
// one 64-lane wave per node, lane = feature channel
__global__ __launch_bounds__(256) void k_gather(const float* __restrict__ feat,
                                                const int* __restrict__ rowptr,
                                                const int2* __restrict__ pairs,
                                                float* __restrict__ out, int n_nodes) {
  int node = blockIdx.x * 4 + (threadIdx.x >> 6);
  int lane = threadIdx.x & 63;
  if (node >= n_nodes) return;
  int beg = rowptr[node], end = rowptr[node + 1];
  float acc = 0.f;
  int j = beg;
  for (; j + 4 <= end; j += 4) {
    int2 p0 = pairs[j], p1 = pairs[j + 1], p2 = pairs[j + 2], p3 = pairs[j + 3];
    float f0 = feat[(size_t)p0.x * 64 + lane];
    float f1 = feat[(size_t)p1.x * 64 + lane];
    float f2 = feat[(size_t)p2.x * 64 + lane];
    float f3 = feat[(size_t)p3.x * 64 + lane];
    acc = fmaf(f0, __int_as_float(p0.y), acc);
    acc = fmaf(f1, __int_as_float(p1.y), acc);
    acc = fmaf(f2, __int_as_float(p2.y), acc);
    acc = fmaf(f3, __int_as_float(p3.y), acc);
  }
  for (; j < end; ++j) {
    int2 p = pairs[j];
    acc = fmaf(feat[(size_t)p.x * 64 + lane], __int_as_float(p.y), acc);
  }
  out[(size_t)node * 64 + lane] = acc;
}

// ---------------- post layer 1: h1r = relu(agg + h*dinv^2 + b1) ---------------
__global__ __launch_bounds__(256) void k_post1(const float* __restrict__ agg,
                                               const float* __restrict__ h,
                                               const float* __restrict__ dinv,
                                               const float* __restrict__ b1,
                                               float* __restrict__ outp,
                                               int n_nodes) {
  int t = blockIdx.x * 256 + threadIdx.x;
  if (t >= n_nodes * 16) return;
  int i = t >> 4;
  int c = (t & 15) << 2;
  float di = dinv[i];
  float w = di * di;
  float4 av = *(const float4*)&agg[(size_t)t * 4];
  float4 hv = *(const float4*)&h[(size_t)t * 4];
  float4 bv = *(const float4*)&b1[c];
  float4 r;
  r.x = fmaxf(fmaf(hv.x, w, av.x) + bv.x, 0.f);
  r.y = fmaxf(fmaf(hv.y, w, av.y) + bv.y, 0.f);
  r.z = fmaxf(fmaf(hv.z, w, av.z) + bv.z, 0.f);
  r.w = fmaxf(fmaf(hv.w, w, av.w) + bv.w, 0.f);
  *(float4*)&outp[(size_t)t * 4] = r;
}

// ---------------- post layer 2: out = agg2 + h2*dinv^2 + bias_out -------------
__global__ __launch_bounds__(256) void k_post2(const float* __restrict__ h2,
                                               const float* __restrict__ dinv,
                                               const float* __restrict__ bias,
                                               float* __restrict__ out,
                                               int n_nodes) {
  int t = blockIdx.x * 256 + threadIdx.x;
  if (t >= n_nodes * 16) return;
  int i = t >> 4;
  int c = (t & 15) << 2;
  float di = dinv[i];
  float w = di * di;
  float4 hv = *(const float4*)&h2[(size_t)t * 4];
  float4 bv = *(const float4*)&bias[c];
  float4 ov = *(const float4*)&out[(size_t)t * 4];
  ov.x += fmaf(hv.x, w, bv.x);
  ov.y += fmaf(hv.y, w, bv.y);
  ov.z += fmaf(hv.z, w, bv.z);
  ov.w += fmaf(hv.w, w, bv.w);
  *(float4*)&out[(size_t)t * 4] = ov;
}

extern "C" void kernel_launch(void* const* d_in, const int* in_sizes, int n_in,
                              void* d_out, int out_size, void* d_ws, size_t ws_size,
                              hipStream_t stream) {
  const float* x    = (const float*)d_in[0];
  const int*   ei   = (const int*)d_in[1];
  const float* W1   = (const float*)d_in[2];
  const float* b1   = (const float*)d_in[3];
  const float* W2   = (const float*)d_in[4];
  const float* b2   = (const float*)d_in[5];
  const float* Wlin = (const float*)d_in[6];
  const float* blin = (const float*)d_in[7];
  float* out = (float*)d_out;

  const int n_nodes = in_sizes[0] / DIN;
  const int n_edges = in_sizes[1] / 2;
  const int* src = ei;
  const int* dst = ei + n_edges;

  char* ws = (char*)d_ws;
  const size_t featBytes = (size_t)n_nodes * DH * sizeof(float);
  size_t off = 0;
  auto alloc = [&](size_t bytes) {
    void* p = ws + off;
    off += (bytes + 255) & ~(size_t)255;
    return p;
  };
  float* bufA     = (float*)alloc(featBytes);              // h1, then h2
  float* bufB     = (float*)alloc(featBytes);              // agg1/h1r, then agg2... (gather1 out)
  int2*  pairs    = (int2*)alloc((size_t)n_edges * 8);     // CSR {src, w}
  int*   degi     = (int*)alloc((size_t)n_nodes * 4);
  float* dinv     = (float*)alloc((size_t)n_nodes * 4);
  int*   rowptr   = (int*)alloc(((size_t)n_nodes + 1) * 4);
  int*   cursor   = (int*)alloc((size_t)n_nodes * 4);
  int*   partials = (int*)alloc(512 * 4);
  float* Wc       = (float*)alloc(64 * 64 * 4);
  float* bias_out = (float*)alloc(64 * 4);

  hipMemsetAsync(degi, 0, (size_t)n_nodes * 4, stream);

  k_wc<<<1, 256, 0, stream>>>(W2, b2, Wlin, blin, Wc, bias_out);
  k_deg<<<(n_edges + 255) / 256, 256, 0, stream>>>(dst, n_edges, degi);
  k_dinv<<<(n_nodes + 255) / 256, 256, 0, stream>>>(degi, dinv, n_nodes);

  const int nb = (n_nodes + 1023) / 1024;
  k_scanA<<<nb, 256, 0, stream>>>(degi, n_nodes, rowptr, partials);
  k_scanB<<<1, 64, 0, stream>>>(partials, nb, rowptr + n_nodes);
  k_scanC<<<(n_nodes + 255) / 256, 256, 0, stream>>>(rowptr, partials, n_nodes, cursor);
  k_scatter<<<(n_edges + 255) / 256, 256, 0, stream>>>(src, dst, dinv, cursor, pairs, n_edges);

  const int gblocks = (n_nodes + 63) / 64;
  const int agblocks = (n_nodes + 3) / 4;
  const int pblocks = (n_nodes * 16 + 255) / 256;

  // layer 1
  k_gemm<<<gblocks, 256, 0, stream>>>(x, W1, bufA, n_nodes, DIN);
  k_gather<<<agblocks, 256, 0, stream>>>(bufA, rowptr, pairs, bufB, n_nodes);
  k_post1<<<pblocks, 256, 0, stream>>>(bufB, bufA, dinv, b1, bufB, n_nodes);

  // layer 2 (+ folded final linear): h2 = h1r @ (W2@Wlin)
  k_gemm<<<gblocks, 256, 0, stream>>>(bufB, Wc, bufA, n_nodes, DH);
  k_gather<<<agblocks, 256, 0, stream>>>(bufA, rowptr, pairs, out, n_nodes);
  k_post2<<<pblocks, 256, 0, stream>>>(bufA, dinv, bias_out, out, n_nodes);
}